// Round 4
// baseline (99.500 us; speedup 1.0000x reference)
//
#include <hip/hip_runtime.h>
#include <math.h>

#define N_BOXES 10647
#define NUM_CLASSES 80
#define MAX_BOXES 20
#define IOU_T 0.1f
#define SCORE_T 0.3f

// Fixed window threshold. scores ~ U[0,1): E[wcnt] = 10647*0.008 = 85,
// sd 9.2. P(wcnt > 128) ~ 1e-6/class. Violations -> exact Phase E.
#define WND_T 0.992f

#define NT 1024
#define NWAVES (NT / 64)
#define WCAP 128   // window capacity (LDS)

// Single-dispatch role split: 167 transpose tiles + 80 class-NMS + 6 copy.
// 253 blocks <= 256 CUs -> ALL blocks hardware-resident simultaneously
// (16 waves, <=22KB LDS, 48 VGPR: one block always fits a CU), so the
// producer blocks always progress and the consumer spin cannot deadlock.
#define TROWS 64
#define TBLOCKS 167     // ceil(10647 / 64)
#define NMSBLOCKS NUM_CLASSES
#define CPBLOCKS 6
#define GRID_BLOCKS (TBLOCKS + NMSBLOCKS + CPBLOCKS)  // 253

// Workspace slot arrays: per (class, tile) 8 key slots + 8 box slots.
// Every key slot is WRITTEN by the producer (zeros for empty) -> poison-
// safe. >8 candidates in a tile (P ~ 5e-5/run) -> SENTINEL -> Phase E.
#define WSLOTS 8
#define SLOT_N (TBLOCKS * WSLOTS)          // 1336 per class
#define KEYS_N (NUM_CLASSES * SLOT_N)      // 106880 u64 = 855 KB
#define SENTINEL (~0ull)

// ws layout (u64 units):
//   [0, KEYS_N)           keys   (class-major, contiguous per class)
//   [KEYS_N, 3*KEYS_N)    boxes  (float4 = 2 u64 each, same indexing)
//   [3*KEYS_N, +334)      per-tile publish flags (double magic)
#define BOX_OFF KEYS_N
#define FLAG_OFF (KEYS_N * 3)
// 128-bit double-magic publish flag: collision with any fixed poison
// pattern requires both u64s to match -> effectively impossible.
#define MAGIC1 0x9E3779B97F4A7C15ull
#define MAGIC2 0xC2B2AE3D27D4EB4Full

// Output layout (all float32, concatenated):
//   [0)      boxes copy        N_BOXES*4               = 42588
//   [42588)  scores transposed NUM_CLASSES*N_BOXES     = 851760
//   [894348) nms_final         NUM_CLASSES*MAX_BOXES*3 = 4800
#define OUT_OFF_SCORES (N_BOXES * 4)
#define OUT_OFF_NMS (N_BOXES * 4 + NUM_CLASSES * N_BOXES)

// R17: kill the second dispatch. R15/R16 accounting: timed region =
// ~41us poison fill (fixed) + ours (~30us). The k1->k2 boundary (drain of
// 173 blocks + graph node gap) is the largest removable chunk. Stream-K
// style flag protocol replaces it: producer tiles publish slots via
// threadfence + agent-release double-magic flags; consumer class-blocks
// spin on agent-scope loads. Slots now carry candidate BOXES too (k1
// loads its 64 tile boxes with one coalesced wave-load), and D3 resolves
// from wave-0 registers (shfl) instead of chained LDS reads.
#define FOR_K(OP) OP(0) OP(1) OP(2) OP(3) OP(4) OP(5) OP(6) OP(7) OP(8) OP(9) OP(10)

// Reference-exact IoU>T test (individually rounded float32 ops; inter==0 =>
// reference IoU is 0 => not suppressed, divide skipped). First box is the
// SELECTED box (reference's area1 = selected's area, added first).
__device__ __forceinline__ bool iou_gt(float jy1, float jx1, float jy2,
                                       float jx2, float area_j, float4 b) {
    float ty = fmaxf(jy1, b.x);
    float tx = fmaxf(jx1, b.y);
    float by = fminf(jy2, b.z);
    float bx = fminf(jx2, b.w);
    float dy = fmaxf(__fsub_rn(by, ty), 0.0f);
    float dx = fmaxf(__fsub_rn(bx, tx), 0.0f);
    float inter = __fmul_rn(dy, dx);
    if (!(inter > 0.0f)) return false;
    float area_i = __fmul_rn(__fsub_rn(b.z, b.x), __fsub_rn(b.w, b.y));
    float uni = __fsub_rn(__fadd_rn(area_j, area_i), inter);
    float iou = (uni > 0.0f) ? __fdiv_rn(inter, uni) : 0.0f;
    return iou > IOU_T;
}

__global__ __launch_bounds__(NT) void fused_flag_kernel(
    const float* __restrict__ boxes, const float* __restrict__ scores,
    float* __restrict__ out, unsigned long long* __restrict__ ws) {
    const int tid = threadIdx.x;
    const int b = blockIdx.x;
    const int wave = tid >> 6;
    const int lane = tid & 63;
    const float4* boxes4 = (const float4*)boxes;

    // =======================================================================
    // Role 3: boxes copy (blocks 247..252)
    // =======================================================================
    if (b >= TBLOCKS + NMSBLOCKS) {
        for (int q = (b - TBLOCKS - NMSBLOCKS) * NT + tid; q < N_BOXES;
             q += CPBLOCKS * NT) {
            ((float4*)out)[q] = ((const float4*)boxes)[q];
        }
        return;
    }

    // =======================================================================
    // Role 1: transpose tile + slot producer (blocks 0..166)
    // =======================================================================
    if (b < TBLOCKS) {
        __shared__ float lds[TROWS * 81];  // pad 81 -> conflict-free
        __shared__ float4 s_tb[TROWS];     // this tile's boxes
        const int r0 = b * TROWS;
        const int nr = min(TROWS, N_BOXES - r0);

        // Tile boxes: one coalesced wave-load (64 x 16B contiguous).
        if (tid < TROWS) {
            s_tb[tid] = (r0 + tid < N_BOXES) ? boxes4[r0 + tid]
                                             : make_float4(0.f, 0.f, 0.f, 0.f);
        }

        // Read: contiguous chunk scores[r0*80 .. (r0+nr)*80), float4 loads.
        const int nq = nr * 20;  // 80 floats/row = 20 float4/row
        for (int q = tid; q < nq; q += NT) {
            const int r = q / 20;
            const int c4 = (q - r * 20) * 4;
            float4 v = *(const float4*)(scores + (r0 + r) * NUM_CLASSES + c4);
            float* dst = &lds[r * 81 + c4];
            dst[0] = v.x;
            dst[1] = v.y;
            dst[2] = v.z;
            dst[3] = v.w;
        }
        __syncthreads();

        // Write: wave chi owns classes {p*16+chi}; lane = row. Per class:
        // (a) transposed-column store (256 B contiguous per wave),
        // (b) candidate ballot -> rank-compacted key+box slot writes.
        unsigned long long* wskeys = ws;
        float4* wsboxes = (float4*)(ws + BOX_OFF);
        const int r = tid & (TROWS - 1);
        const int chi = tid >> 6;
        #pragma unroll
        for (int p = 0; p < 5; ++p) {
            const int c = p * 16 + chi;
            float v = 0.0f;
            if (r < nr) {
                v = lds[r * 81 + c];
                out[OUT_OFF_SCORES + c * N_BOXES + r0 + r] = v;
            }
            const bool cand = (r < nr) && (v >= WND_T);
            const unsigned long long mask = __ballot(cand);
            const int cnt = __popcll(mask);
            const int base = (c * TBLOCKS + b) * WSLOTS;
            if (cnt <= WSLOTS) {
                if (cand) {
                    const int rank = __popcll(mask & ((1ull << r) - 1ull));
                    wskeys[base + rank] =
                        ((unsigned long long)__float_as_uint(v) << 32) |
                        (0xFFFFFFFFu - (unsigned)(r0 + r));
                    wsboxes[base + rank] = s_tb[r];
                }
                if (r >= cnt && r < WSLOTS) wskeys[base + r] = 0ull;
            } else {
                // pathological tie burst -> sentinel -> consumer Phase E
                if (r == 0) wskeys[base] = SENTINEL;
                if (r >= 1 && r < WSLOTS) wskeys[base + r] = 0ull;
            }
        }

        // Publish: all stores complete (syncthreads drains vmcnt), one
        // L2 writeback, then agent-release double-magic flag.
        __syncthreads();
        if (tid == 0) {
            __threadfence();
            unsigned long long* flg = ws + FLAG_OFF;
            __hip_atomic_store(&flg[2 * b], MAGIC1, __ATOMIC_RELEASE,
                               __HIP_MEMORY_SCOPE_AGENT);
            __hip_atomic_store(&flg[2 * b + 1], MAGIC2, __ATOMIC_RELEASE,
                               __HIP_MEMORY_SCOPE_AGENT);
        }
        return;
    }

    // =======================================================================
    // Role 2: per-class NMS consumer (blocks 167..246), c = b - TBLOCKS
    // =======================================================================
    const int c = b - TBLOCKS;
    const float* col = out + OUT_OFF_SCORES + c * N_BOXES;  // Phase E only

    __shared__ unsigned long long s_k[WCAP];        // window keys (unsorted)
    __shared__ float4 s_b4[WCAP];                   // window boxes (unsorted)
    __shared__ unsigned long long s_ks[WCAP];       // sorted keys
    __shared__ float4 s_bs[WCAP];                   // sorted boxes
    __shared__ __align__(16) unsigned long long s_mask[WCAP][2];
    __shared__ unsigned long long s_rk[2][NWAVES];  // fallback reduce
    __shared__ int s_out[MAX_BOXES];
    __shared__ int s_cnt, s_nsel, s_ovf;

    if (tid < MAX_BOXES) s_out[tid] = -1;
    if (tid == 0) { s_cnt = 0; s_nsel = 0; s_ovf = 0; }

    // ---- spin until all 167 tiles published (wave 0 polls) ----
    if (wave == 0) {
        const unsigned long long* flg = ws + FLAG_OFF;
        bool ok = false;
        while (!ok) {
            bool mine = true;
            #pragma unroll
            for (int q = 0; q < 6; ++q) {
                const int idx = lane + q * 64;
                if (idx < 2 * TBLOCKS) {
                    unsigned long long v = __hip_atomic_load(
                        &flg[idx], __ATOMIC_RELAXED,
                        __HIP_MEMORY_SCOPE_AGENT);
                    mine = mine && (v == ((idx & 1) ? MAGIC2 : MAGIC1));
                }
            }
            ok = (__ballot(mine) == ~0ull);
            if (!ok) __builtin_amdgcn_s_sleep(16);
        }
    }
    __syncthreads();
    __threadfence();  // acquire: slot/column reads ordered after flags

    // ---- Phase C': slot scan (keys 10.7 KB + boxes coalesced) ----
    const unsigned long long* wsk = ws + (size_t)c * SLOT_N;
    const float4* wsb = ((const float4*)(ws + BOX_OFF)) + (size_t)c * SLOT_N;
    for (int q = tid; q < SLOT_N; q += NT) {
        unsigned long long s = wsk[q];
        bool val = false;
        if (s != 0ull) {
            if ((unsigned)(s >> 32) >= 0x3F800000u) {
                s_ovf = 1;  // sentinel (benign same-value LDS race)
            } else {
                val = true;
            }
        }
        const unsigned long long m = __ballot(val);
        int basew = 0;
        if (lane == 0 && m) basew = atomicAdd(&s_cnt, __popcll(m));
        basew = __shfl(basew, 0);
        if (val) {
            const int pos = basew + __popcll(m & ((1ull << lane) - 1ull));
            if (pos < WCAP) {
                s_k[pos] = s;
                s_b4[pos] = wsb[q];  // box rode along in the slot
            }
        }
    }
    __syncthreads();

    const int wcnt = s_cnt;
    const bool overflow = (wcnt > WCAP) || (s_ovf != 0);

    // ---- Phase D1: parallel rank sort (threads 0..wcnt) ----
    if (!overflow && tid < wcnt) {
        const unsigned long long mykey = s_k[tid];
        const float4 mybox = s_b4[tid];
        int rank = 0;
        for (int j = 0; j < wcnt; ++j) rank += (s_k[j] > mykey) ? 1 : 0;
        s_ks[rank] = mykey;
        s_bs[rank] = mybox;
    }
    __syncthreads();

    // ---- Phase D2: parallel suppression bit-matrix (ballot per task) ----
    if (!overflow) {
        const int ntask = 2 * wcnt;
        for (int t = wave; t < ntask; t += NWAVES) {
            const int row = t >> 1, ch = t & 1;
            float4 rb = s_bs[row];
            float area_r =
                __fmul_rn(__fsub_rn(rb.z, rb.x), __fsub_rn(rb.w, rb.y));
            int colj = ch * 64 + lane;
            bool s = (colj < wcnt) &&
                     iou_gt(rb.x, rb.y, rb.z, rb.w, area_r, s_bs[colj]);
            unsigned long long m = __ballot(s);
            if (lane == 0) s_mask[row][ch] = m;
        }
    }
    __syncthreads();

    // ---- Phase D3: serial resolve, masks/keys in wave-0 registers.
    // Chain per iter: ctz -> shfl broadcast (~40cy) -> bit ops; no LDS
    // round-trip on the critical path.
    if (wave == 0 && !overflow) {
        const unsigned long long pA0 = s_mask[lane][0];
        const unsigned long long pA1 = s_mask[lane][1];
        const unsigned long long pB0 = s_mask[64 + lane][0];
        const unsigned long long pB1 = s_mask[64 + lane][1];
        const unsigned long long kA = s_ks[lane];
        const unsigned long long kB = s_ks[64 + lane];
        unsigned long long a0, a1;
        if (wcnt >= 64) {
            a0 = ~0ull;
            a1 = (wcnt >= 128) ? ~0ull
                               : ((wcnt > 64) ? ((1ull << (wcnt - 64)) - 1)
                                              : 0ull);
        } else {
            a0 = (wcnt > 0) ? ((1ull << wcnt) - 1) : 0ull;
            a1 = 0ull;
        }
        int nkept = 0;
        while ((a0 | a1) != 0 && nkept < MAX_BOXES) {
            int pos;
            unsigned long long mx, my, kk;
            if (a0) {  // wave-uniform branch
                pos = __builtin_ctzll(a0);
                mx = __shfl(pA0, pos);
                my = __shfl(pA1, pos);
                kk = __shfl(kA, pos);
            } else {
                const int p1 = __builtin_ctzll(a1);
                mx = __shfl(pB0, p1);
                my = __shfl(pB1, p1);
                kk = __shfl(kB, p1);
                pos = 64 + p1;
            }
            if (lane == 0)
                s_out[nkept] = (int)(0xFFFFFFFFu - (unsigned int)kk);
            ++nkept;
            a0 &= ~mx;
            a1 &= ~my;
            if (pos < 64) a0 &= ~(1ull << pos);
            else a1 &= ~(1ull << (pos - 64));
        }
        if (lane == 0) s_nsel = nkept;
    }
    __syncthreads();

    // ---- Phase E: exact fallback (window exhausted / overflow). Never
    // triggers on typical data; correctness path only.
    const int nsel0 = s_nsel;
    const bool needs_more = (nsel0 < MAX_BOXES);
    if (needs_more) {
#define DECL_K(k) unsigned long long k_##k = 0;
        FOR_K(DECL_K)
#undef DECL_K
#define BUILDE_K(k)                                                      \
        {                                                                \
            int i = tid + (k)*NT;                                        \
            if (i < N_BOXES) {                                           \
                float v = col[i];                                        \
                if (v >= SCORE_T) {                                      \
                    bool dead = (!overflow && v >= WND_T);               \
                    if (!dead && nsel0 > 0) {                            \
                        float4 bi = boxes4[i];                           \
                        for (int j = 0; j < nsel0; ++j) {                \
                            float4 sb = boxes4[s_out[j]];                \
                            float aj =                                   \
                                __fmul_rn(__fsub_rn(sb.z, sb.x),         \
                                          __fsub_rn(sb.w, sb.y));        \
                            if (iou_gt(sb.x, sb.y, sb.z, sb.w, aj,       \
                                       bi)) {                            \
                                dead = true;                             \
                                break;                                   \
                            }                                            \
                        }                                                \
                    }                                                    \
                    if (!dead)                                           \
                        k_##k = ((unsigned long long)__float_as_uint(v)  \
                                 << 32) |                                \
                                (0xFFFFFFFFu - (unsigned int)i);         \
                }                                                        \
            }                                                            \
        }
        FOR_K(BUILDE_K)
#undef BUILDE_K
        #pragma unroll 1
        for (int slot = nsel0; slot < MAX_BOXES; ++slot) {
            unsigned long long bk = 0;
#define MAXK_K(k) if (k_##k > bk) bk = k_##k;
            FOR_K(MAXK_K)
#undef MAXK_K
            #pragma unroll
            for (int off = 32; off >= 1; off >>= 1) {
                unsigned long long o =
                    (unsigned long long)__shfl_xor((long long)bk, off);
                if (o > bk) bk = o;
            }
            const int par = slot & 1;
            if (lane == 0) s_rk[par][wave] = bk;
            __syncthreads();
            unsigned long long f = s_rk[par][0];
            #pragma unroll
            for (int w = 1; w < NWAVES; ++w) {
                unsigned long long o = s_rk[par][w];
                if (o > f) f = o;
            }
            if (f == 0) break;  // uniform
            const int widx = (int)(0xFFFFFFFFu - (unsigned int)f);
            if (tid == 0) s_out[slot] = widx;
            float4 wb = boxes4[widx];  // uniform L1 broadcast
            const float area_j =
                __fmul_rn(__fsub_rn(wb.z, wb.x), __fsub_rn(wb.w, wb.y));
#define SCANE_K(k)                                                      \
            if (k_##k != 0) {                                           \
                int i = tid + (k)*NT;                                   \
                float4 bb = boxes4[i];                                  \
                if (i == widx ||                                        \
                    iou_gt(wb.x, wb.y, wb.z, wb.w, area_j, bb))         \
                    k_##k = 0;                                          \
            }
            FOR_K(SCANE_K)
#undef SCANE_K
        }
    }

    // ---- emit rows ----
    __syncthreads();
    if (tid < MAX_BOXES) {
        int bi = s_out[tid];
        int o = OUT_OFF_NMS + c * MAX_BOXES * 3 + tid * 3;
        if (bi >= 0) {
            out[o + 0] = 0.0f;
            out[o + 1] = (float)c;
            out[o + 2] = (float)bi;
        } else {
            out[o + 0] = -1.0f;
            out[o + 1] = -1.0f;
            out[o + 2] = -1.0f;
        }
    }
}

extern "C" void kernel_launch(void* const* d_in, const int* in_sizes, int n_in,
                              void* d_out, int out_size, void* d_ws,
                              size_t ws_size, hipStream_t stream) {
    const float* boxes = (const float*)d_in[0];   // [N,4] fp32
    const float* scores = (const float*)d_in[1];  // [N,C] fp32
    float* out = (float*)d_out;
    unsigned long long* ws = (unsigned long long*)d_ws;  // ~2.6 MB used

    // Single dispatch: producer tiles publish slots via double-magic flags;
    // consumer class-blocks spin (all 253 blocks co-resident on 256 CUs).
    fused_flag_kernel<<<GRID_BLOCKS, NT, 0, stream>>>(boxes, scores, out, ws);
}

// Round 5
// 72.437 us; speedup vs baseline: 1.3736x; 1.3736x over previous
//
#include <hip/hip_runtime.h>
#include <math.h>

#define N_BOXES 10647
#define NUM_CLASSES 80
#define MAX_BOXES 20
#define IOU_T 0.1f
#define SCORE_T 0.3f

// Fixed window threshold. scores ~ U[0,1): E[wcnt] = 10647*0.008 = 85,
// sd 9.2. P(wcnt > 128) ~ 1e-6/class. Violations -> exact Phase E.
#define WND_T 0.992f

#define NT 1024
#define NWAVES (NT / 64)
#define WCAP 128   // window capacity (LDS)

// k1: 167 transpose/slot tiles (nothing else -> shortest dependency edge).
// k2: 80 NMS blocks + 6 boxes-copy blocks (copy overlaps NMS latency).
#define TROWS 64
#define TBLOCKS 167     // ceil(10647 / 64)
#define CPBLOCKS 6
#define K2_BLOCKS (NUM_CLASSES + CPBLOCKS)

// Workspace slots: per (class, tile) 8 key slots + 8 box slots. Every KEY
// slot is written by k1 (zeros for empty) -> poison-safe. Box slots are
// written iff the key slot is valid and read iff valid. >8 candidates in
// one tile (P ~ 5e-5/run) -> SENTINEL -> exact Phase E.
#define WSLOTS 8
#define SLOT_N (TBLOCKS * WSLOTS)          // 1336 per class
#define KEYS_N (NUM_CLASSES * SLOT_N)      // 106880 u64 = 855 KB
#define SENTINEL (~0ull)
#define BOX_OFF KEYS_N                     // float4 boxes, same indexing

// Output layout (all float32, concatenated):
//   [0)      boxes copy        N_BOXES*4               = 42588
//   [42588)  scores transposed NUM_CLASSES*N_BOXES     = 851760
//   [894348) nms_final         NUM_CLASSES*MAX_BOXES*3 = 4800
#define OUT_OFF_SCORES (N_BOXES * 4)
#define OUT_OFF_NMS (N_BOXES * 4 + NUM_CLASSES * N_BOXES)

// R18: R17 proved single-dispatch handoff (fences/flag-spin) costs more
// than a kernel boundary (47.5us alone vs ~30us for the whole 2-kernel
// path). Keep R16's two-dispatch skeleton; graft R17's two orthogonal
// wins into it: (1) boxes ride in slots -> k2 does no random cold-HBM
// box gathers (poison fill evicts L3 every iter); (2) D3 resolves from
// wave-0 registers via shfl, no chained LDS reads. Also: boxes-copy
// moved k1->k2 so k2's start (= k1 last-block finish) comes sooner.
#define FOR_K(OP) OP(0) OP(1) OP(2) OP(3) OP(4) OP(5) OP(6) OP(7) OP(8) OP(9) OP(10)

// Reference-exact IoU>T test (individually rounded float32 ops; inter==0 =>
// reference IoU is 0 => not suppressed, divide skipped). First box is the
// SELECTED box (reference's area1 = selected's area, added first).
__device__ __forceinline__ bool iou_gt(float jy1, float jx1, float jy2,
                                       float jx2, float area_j, float4 b) {
    float ty = fmaxf(jy1, b.x);
    float tx = fmaxf(jx1, b.y);
    float by = fminf(jy2, b.z);
    float bx = fminf(jx2, b.w);
    float dy = fmaxf(__fsub_rn(by, ty), 0.0f);
    float dx = fmaxf(__fsub_rn(bx, tx), 0.0f);
    float inter = __fmul_rn(dy, dx);
    if (!(inter > 0.0f)) return false;
    float area_i = __fmul_rn(__fsub_rn(b.z, b.x), __fsub_rn(b.w, b.y));
    float uni = __fsub_rn(__fadd_rn(area_j, area_i), inter);
    float iou = (uni > 0.0f) ? __fdiv_rn(inter, uni) : 0.0f;
    return iou > IOU_T;
}

// ---------------------------------------------------------------------------
// Kernel 1: coalesced transpose of scores [N,C]->[C,N] into out, plus
// per-(class,tile) candidate key+box slot writes into ws. 167 blocks only.
// ---------------------------------------------------------------------------
__global__ __launch_bounds__(NT) void transpose_slots_kernel(
    const float* __restrict__ boxes, const float* __restrict__ scores,
    float* __restrict__ out, unsigned long long* __restrict__ ws) {
    const int tid = threadIdx.x;
    const int b = blockIdx.x;

    __shared__ float lds[TROWS * 81];  // [r][c], pad 81 -> conflict-free
    __shared__ float4 s_tb[TROWS];     // this tile's boxes
    const int r0 = b * TROWS;
    const int nr = min(TROWS, N_BOXES - r0);

    // Tile boxes: one coalesced wave-load (64 x 16B contiguous).
    if (tid < TROWS) {
        s_tb[tid] = (r0 + tid < N_BOXES)
                        ? ((const float4*)boxes)[r0 + tid]
                        : make_float4(0.f, 0.f, 0.f, 0.f);
    }

    // Read: contiguous chunk scores[r0*80 .. (r0+nr)*80), float4 loads.
    const int nq = nr * 20;  // 80 floats/row = 20 float4/row
    for (int q = tid; q < nq; q += NT) {
        const int r = q / 20;
        const int c4 = (q - r * 20) * 4;
        float4 v = *(const float4*)(scores + (r0 + r) * NUM_CLASSES + c4);
        float* dst = &lds[r * 81 + c4];
        dst[0] = v.x;
        dst[1] = v.y;
        dst[2] = v.z;
        dst[3] = v.w;
    }
    __syncthreads();

    // Write: wave chi owns classes {p*16+chi}; lane = row. Per class:
    // (a) transposed-column store (256 B contiguous per wave),
    // (b) candidate ballot -> rank-compacted key+box slot writes.
    unsigned long long* wskeys = ws;
    float4* wsboxes = (float4*)(ws + BOX_OFF);
    const int r = tid & (TROWS - 1);
    const int chi = tid >> 6;
    #pragma unroll
    for (int p = 0; p < 5; ++p) {
        const int c = p * 16 + chi;
        float v = 0.0f;
        if (r < nr) {
            v = lds[r * 81 + c];
            out[OUT_OFF_SCORES + c * N_BOXES + r0 + r] = v;
        }
        const bool cand = (r < nr) && (v >= WND_T);
        const unsigned long long mask = __ballot(cand);
        const int cnt = __popcll(mask);
        const int base = (c * TBLOCKS + b) * WSLOTS;
        if (cnt <= WSLOTS) {
            if (cand) {
                const int rank = __popcll(mask & ((1ull << r) - 1ull));
                wskeys[base + rank] =
                    ((unsigned long long)__float_as_uint(v) << 32) |
                    (0xFFFFFFFFu - (unsigned)(r0 + r));
                wsboxes[base + rank] = s_tb[r];
            }
            if (r >= cnt && r < WSLOTS) wskeys[base + r] = 0ull;
        } else {
            // pathological tie burst -> sentinel -> k2 overflow -> Phase E
            if (r == 0) wskeys[base] = SENTINEL;
            if (r >= 1 && r < WSLOTS) wskeys[base + r] = 0ull;
        }
    }
}

// ---------------------------------------------------------------------------
// Kernel 2: per-class NMS from pre-compacted slots (blocks 0..79) + boxes
// copy (blocks 80..85, overlaps NMS latency). Main path never touches the
// score column or the boxes array; Phase E (exact fallback) re-scans the
// transposed column written by kernel 1.
// ---------------------------------------------------------------------------
__global__ __launch_bounds__(NT) void nms_kernel(
    const float* __restrict__ boxes, float* __restrict__ out,
    const unsigned long long* __restrict__ ws) {
    const int tid = threadIdx.x;
    const int c = blockIdx.x;

    if (c >= NUM_CLASSES) {
        // ---- boxes copy: coalesced both sides, independent of k1 ----
        for (int q = (c - NUM_CLASSES) * NT + tid; q < N_BOXES;
             q += CPBLOCKS * NT) {
            ((float4*)out)[q] = ((const float4*)boxes)[q];
        }
        return;
    }

    const int wave = tid >> 6;
    const int lane = tid & 63;
    const float4* boxes4 = (const float4*)boxes;
    const float* col = out + OUT_OFF_SCORES + c * N_BOXES;  // Phase E only

    __shared__ unsigned long long s_k[WCAP];        // window keys (unsorted)
    __shared__ float4 s_b4[WCAP];                   // window boxes (unsorted)
    __shared__ unsigned long long s_ks[WCAP];       // sorted keys
    __shared__ float4 s_bs[WCAP];                   // sorted boxes
    __shared__ __align__(16) unsigned long long s_mask[WCAP][2];
    __shared__ unsigned long long s_rk[2][NWAVES];  // fallback reduce
    __shared__ int s_out[MAX_BOXES];
    __shared__ int s_cnt, s_nsel, s_ovf;

    if (tid < MAX_BOXES) s_out[tid] = -1;
    if (tid == 0) { s_cnt = 0; s_nsel = 0; s_ovf = 0; }
    __syncthreads();

    // ---- Phase C': slot scan (keys 10.7 KB, L2-warm from k1) ----
    const unsigned long long* wsk = ws + (size_t)c * SLOT_N;
    const float4* wsb = ((const float4*)(ws + BOX_OFF)) + (size_t)c * SLOT_N;
    for (int q = tid; q < SLOT_N; q += NT) {
        unsigned long long s = wsk[q];
        bool val = false;
        if (s != 0ull) {
            if ((unsigned)(s >> 32) >= 0x3F800000u) {
                s_ovf = 1;  // sentinel (benign same-value LDS race)
            } else {
                val = true;
            }
        }
        const unsigned long long m = __ballot(val);
        int basew = 0;
        if (lane == 0 && m) basew = atomicAdd(&s_cnt, __popcll(m));
        basew = __shfl(basew, 0);
        if (val) {
            const int pos = basew + __popcll(m & ((1ull << lane) - 1ull));
            if (pos < WCAP) {
                s_k[pos] = s;
                s_b4[pos] = wsb[q];  // box rode along in the slot (L2-warm)
            }
        }
    }
    __syncthreads();

    const int wcnt = s_cnt;
    const bool overflow = (wcnt > WCAP) || (s_ovf != 0);

    // ---- Phase D1: parallel rank sort (threads 0..wcnt). rank_i =
    // #{j : key_j > key_i}; keys unique -> permutation.
    if (!overflow && tid < wcnt) {
        const unsigned long long mykey = s_k[tid];
        const float4 mybox = s_b4[tid];
        int rank = 0;
        for (int j = 0; j < wcnt; ++j) rank += (s_k[j] > mykey) ? 1 : 0;
        s_ks[rank] = mykey;
        s_bs[rank] = mybox;
    }
    __syncthreads();

    // ---- Phase D2: parallel suppression bit-matrix. Task t = (row,chunk):
    // lane computes iou_gt(row, chunk*64+lane); one ballot per task.
    // Row = selected-box role (reference op order).
    if (!overflow) {
        const int ntask = 2 * wcnt;
        for (int t = wave; t < ntask; t += NWAVES) {
            const int row = t >> 1, ch = t & 1;
            float4 rb = s_bs[row];
            float area_r =
                __fmul_rn(__fsub_rn(rb.z, rb.x), __fsub_rn(rb.w, rb.y));
            int colj = ch * 64 + lane;
            bool s = (colj < wcnt) &&
                     iou_gt(rb.x, rb.y, rb.z, rb.w, area_r, s_bs[colj]);
            unsigned long long m = __ballot(s);
            if (lane == 0) s_mask[row][ch] = m;
        }
    }
    __syncthreads();

    // ---- Phase D3: serial resolve, masks/keys in wave-0 registers.
    // Chain per iter: ctz -> shfl broadcast (~40cy) -> bit ops; no LDS
    // round-trip on the critical path.
    if (wave == 0 && !overflow) {
        const unsigned long long pA0 = s_mask[lane][0];
        const unsigned long long pA1 = s_mask[lane][1];
        const unsigned long long pB0 = s_mask[64 + lane][0];
        const unsigned long long pB1 = s_mask[64 + lane][1];
        const unsigned long long kA = s_ks[lane];
        const unsigned long long kB = s_ks[64 + lane];
        unsigned long long a0, a1;
        if (wcnt >= 64) {
            a0 = ~0ull;
            a1 = (wcnt >= 128) ? ~0ull
                               : ((wcnt > 64) ? ((1ull << (wcnt - 64)) - 1)
                                              : 0ull);
        } else {
            a0 = (wcnt > 0) ? ((1ull << wcnt) - 1) : 0ull;
            a1 = 0ull;
        }
        int nkept = 0;
        while ((a0 | a1) != 0 && nkept < MAX_BOXES) {
            int pos;
            unsigned long long mx, my, kk;
            if (a0) {  // wave-uniform branch
                pos = __builtin_ctzll(a0);
                mx = __shfl(pA0, pos);
                my = __shfl(pA1, pos);
                kk = __shfl(kA, pos);
            } else {
                const int p1 = __builtin_ctzll(a1);
                mx = __shfl(pB0, p1);
                my = __shfl(pB1, p1);
                kk = __shfl(kB, p1);
                pos = 64 + p1;
            }
            if (lane == 0)
                s_out[nkept] = (int)(0xFFFFFFFFu - (unsigned int)kk);
            ++nkept;
            a0 &= ~mx;
            a1 &= ~my;
            if (pos < 64) a0 &= ~(1ull << pos);
            else a1 &= ~(1ull << (pos - 64));
        }
        if (lane == 0) s_nsel = nkept;
    }
    __syncthreads();

    // ---- Phase E: exact fallback (window exhausted early / overflow).
    // Invariant: if !overflow and nsel0 < 20, every window member (score >=
    // WND_T) was examined (kept or suppressed) -> all dead; others checked
    // against the selected set. Never triggers on typical data.
    const int nsel0 = s_nsel;
    const bool needs_more = (nsel0 < MAX_BOXES);
    if (needs_more) {
#define DECL_K(k) unsigned long long k_##k = 0;
        FOR_K(DECL_K)
#undef DECL_K
#define BUILDE_K(k)                                                      \
        {                                                                \
            int i = tid + (k)*NT;                                        \
            if (i < N_BOXES) {                                           \
                float v = col[i];                                        \
                if (v >= SCORE_T) {                                      \
                    bool dead = (!overflow && v >= WND_T);               \
                    if (!dead && nsel0 > 0) {                            \
                        float4 bi = boxes4[i];                           \
                        for (int j = 0; j < nsel0; ++j) {                \
                            float4 sb = boxes4[s_out[j]];                \
                            float aj =                                   \
                                __fmul_rn(__fsub_rn(sb.z, sb.x),         \
                                          __fsub_rn(sb.w, sb.y));        \
                            if (iou_gt(sb.x, sb.y, sb.z, sb.w, aj,       \
                                       bi)) {                            \
                                dead = true;                             \
                                break;                                   \
                            }                                            \
                        }                                                \
                    }                                                    \
                    if (!dead)                                           \
                        k_##k = ((unsigned long long)__float_as_uint(v)  \
                                 << 32) |                                \
                                (0xFFFFFFFFu - (unsigned int)i);         \
                }                                                        \
            }                                                            \
        }
        FOR_K(BUILDE_K)
#undef BUILDE_K
        #pragma unroll 1
        for (int slot = nsel0; slot < MAX_BOXES; ++slot) {
            unsigned long long bk = 0;
#define MAXK_K(k) if (k_##k > bk) bk = k_##k;
            FOR_K(MAXK_K)
#undef MAXK_K
            #pragma unroll
            for (int off = 32; off >= 1; off >>= 1) {
                unsigned long long o =
                    (unsigned long long)__shfl_xor((long long)bk, off);
                if (o > bk) bk = o;
            }
            const int par = slot & 1;
            if (lane == 0) s_rk[par][wave] = bk;
            __syncthreads();
            unsigned long long f = s_rk[par][0];
            #pragma unroll
            for (int w = 1; w < NWAVES; ++w) {
                unsigned long long o = s_rk[par][w];
                if (o > f) f = o;
            }
            if (f == 0) break;  // uniform
            const int widx = (int)(0xFFFFFFFFu - (unsigned int)f);
            if (tid == 0) s_out[slot] = widx;
            float4 wb = boxes4[widx];  // uniform L1 broadcast
            const float area_j =
                __fmul_rn(__fsub_rn(wb.z, wb.x), __fsub_rn(wb.w, wb.y));
#define SCANE_K(k)                                                      \
            if (k_##k != 0) {                                           \
                int i = tid + (k)*NT;                                   \
                float4 bb = boxes4[i];                                  \
                if (i == widx ||                                        \
                    iou_gt(wb.x, wb.y, wb.z, wb.w, area_j, bb))         \
                    k_##k = 0;                                          \
            }
            FOR_K(SCANE_K)
#undef SCANE_K
        }
    }

    // ---- emit rows ----
    __syncthreads();
    if (tid < MAX_BOXES) {
        int bi = s_out[tid];
        int o = OUT_OFF_NMS + c * MAX_BOXES * 3 + tid * 3;
        if (bi >= 0) {
            out[o + 0] = 0.0f;
            out[o + 1] = (float)c;
            out[o + 2] = (float)bi;
        } else {
            out[o + 0] = -1.0f;
            out[o + 1] = -1.0f;
            out[o + 2] = -1.0f;
        }
    }
}

extern "C" void kernel_launch(void* const* d_in, const int* in_sizes, int n_in,
                              void* d_out, int out_size, void* d_ws,
                              size_t ws_size, hipStream_t stream) {
    const float* boxes = (const float*)d_in[0];   // [N,4] fp32
    const float* scores = (const float*)d_in[1];  // [N,C] fp32
    float* out = (float*)d_out;
    unsigned long long* ws = (unsigned long long*)d_ws;  // ~2.6 MB used

    // Launch 1: transpose + key/box slot production (167 blocks only —
    // shortest possible dependency edge for k2).
    transpose_slots_kernel<<<TBLOCKS, NT, 0, stream>>>(boxes, scores, out, ws);
    // Launch 2: NMS from slots (80 blocks) + boxes copy (6 blocks, runs in
    // the NMS blocks' latency shadow).
    nms_kernel<<<K2_BLOCKS, NT, 0, stream>>>(boxes, out, ws);
}